// Round 2
// baseline (220.804 us; speedup 1.0000x reference)
//
#include <hip/hip_runtime.h>

// x: [8, 1, 160, 160, 160] fp32; log_sigma: [3] fp32; out: scalar fp32.
// loss = -(mean_d(k) + mean_h(k) + mean_w(k)) / 3, k = exp(-sq/(2*sigma^2)),
// sq[b][pair] = sum over remaining dims of adjacent-slice squared diff.

constexpr int Wd = 160;
constexpr int SLICE = 160 * 160;          // floats per (b,d) slice
constexpr long BSTRIDE = 160L * 25600;    // floats per batch
constexpr int NB = 8;
constexpr int NPAIR = 159;                // slice pairs per axis
constexpr int WS_FLOATS = 3 * NB * NPAIR; // 3816

__global__ void zero_ws_kernel(float* __restrict__ ws) {
    int i = blockIdx.x * 256 + threadIdx.x;
    if (i < WS_FLOATS) ws[i] = 0.f;
}

// Grid: 8 b * 10 h-chunks * 16 d-segments = 1280 blocks (5/CU exact), 320 thr.
// Thread t: float4 col fw=t%40, rows r1=t/40 (0..7) and r2=r1+8.
// Software-pipelined: slice it+1 loaded into regs at TOP of iter it; compute
// on slice it (regs + LDS[it&1]); ds_write of next + one barrier at bottom.
__global__ __launch_bounds__(320) void diff3_kernel(const float* __restrict__ x,
                                                    float* __restrict__ ws) {
    __shared__ __align__(16) float buf[2][17 * Wd];
    __shared__ float accD[10];
    __shared__ float accH[16];
    __shared__ float accW[160];

    const int t = threadIdx.x;
    const int bid = blockIdx.x;
    const int b = bid / 160;
    const int rem = bid % 160;
    const int s = rem / 10;    // d-segment 0..15
    const int hc = rem % 10;   // h-chunk 0..9
    const int h0 = hc * 16;
    const int d0 = s * 10;
    const bool lastSeg = (s == 15);          // no trailing d-halo slice

    const int fw = t % 40;
    const int r1 = t / 40;   // 0..7
    const int r2 = r1 + 8;   // 8..15
    const bool halo = (t < 40) && (hc < 9);  // stage row h0+16 (h-halo)
    const bool hOK2 = !(hc == 9 && r1 == 7); // row 159 has no h-pair

    if (t < 10)  accD[t] = 0.f;
    if (t < 16)  accH[t] = 0.f;
    if (t < 160) accW[t] = 0.f;

    const float* xb = x + (size_t)b * BSTRIDE + (size_t)d0 * SLICE
                        + (size_t)h0 * Wd + (size_t)fw * 4;

    // ---- prologue: slice d0 into regs + LDS[0] ----
    float4 c1 = *(const float4*)(xb + r1 * Wd);
    float4 c2 = *(const float4*)(xb + r2 * Wd);
    float4 c3;
    if (halo) c3 = *(const float4*)(xb + 16 * Wd);
    {
        float* Bf = buf[0];
        *(float4*)(Bf + r1 * Wd + fw * 4) = c1;
        *(float4*)(Bf + r2 * Wd + fw * 4) = c2;
        if (halo) *(float4*)(Bf + 16 * Wd + fw * 4) = c3;
    }
    __syncthreads();

    float4 p1, p2;
    float aH1 = 0.f, aH2 = 0.f;
    float aW0 = 0.f, aW1 = 0.f, aW2 = 0.f, aW3 = 0.f;

    for (int it = 0; it < 10; ++it) {
        // -- prefetch slice d0+it+1 into registers (issued ~60 instr before use)
        const bool hasNext = (it < 9) || !lastSeg;
        float4 n1, n2, n3;
        const float* sp = xb + (size_t)(it + 1) * SLICE;
        if (hasNext) {
            n1 = *(const float4*)(sp + r1 * Wd);
            n2 = *(const float4*)(sp + r2 * Wd);
            if (halo && it < 9) n3 = *(const float4*)(sp + 16 * Wd);
        }

        const float* Bf = buf[it & 1];
        // -- w-axis (per-col pairs, accumulated in regs; col fixed per thread)
        float dw;
        dw = c1.y - c1.x; aW0 += dw * dw;
        dw = c1.z - c1.y; aW1 += dw * dw;
        dw = c1.w - c1.z; aW2 += dw * dw;
        dw = c2.y - c2.x; aW0 += dw * dw;
        dw = c2.z - c2.y; aW1 += dw * dw;
        dw = c2.w - c2.z; aW2 += dw * dw;
        if (fw < 39) {
            float b1 = Bf[r1 * Wd + fw * 4 + 4]; dw = b1 - c1.w; aW3 += dw * dw;
            float b2 = Bf[r2 * Wd + fw * 4 + 4]; dw = b2 - c2.w; aW3 += dw * dw;
        }
        // -- h-axis (neighbor row from LDS; r1's pair always exists)
        {
            const float4 hb = *(const float4*)(Bf + (r1 + 1) * Wd + fw * 4);
            float e0 = hb.x - c1.x, e1 = hb.y - c1.y, e2 = hb.z - c1.z, e3 = hb.w - c1.w;
            aH1 += e0 * e0 + e1 * e1 + e2 * e2 + e3 * e3;
        }
        if (hOK2) {
            const float4 hb = *(const float4*)(Bf + (r2 + 1) * Wd + fw * 4);
            float e0 = hb.x - c2.x, e1 = hb.y - c2.y, e2 = hb.z - c2.z, e3 = hb.w - c2.w;
            aH2 += e0 * e0 + e1 * e1 + e2 * e2 + e3 * e3;
        }
        // -- d-axis: pair d0+it-1 (current slice vs previous, regs only)
        if (it > 0) {
            float dx0 = c1.x - p1.x, dx1 = c1.y - p1.y, dx2 = c1.z - p1.z, dx3 = c1.w - p1.w;
            float dy0 = c2.x - p2.x, dy1 = c2.y - p2.y, dy2 = c2.z - p2.z, dy3 = c2.w - p2.w;
            float dd = dx0*dx0 + dx1*dx1 + dx2*dx2 + dx3*dx3
                     + dy0*dy0 + dy1*dy1 + dy2*dy2 + dy3*dy3;
            for (int off = 32; off > 0; off >>= 1) dd += __shfl_down(dd, off, 64);
            if ((t & 63) == 0) atomicAdd(&accD[it - 1], dd);
        }

        p1 = c1; p2 = c2;
        if (hasNext) { c1 = n1; c2 = n2; }
        if (it < 9) {
            float* Nf = buf[(it + 1) & 1];
            *(float4*)(Nf + r1 * Wd + fw * 4) = n1;
            *(float4*)(Nf + r2 * Wd + fw * 4) = n2;
            if (halo) *(float4*)(Nf + 16 * Wd + fw * 4) = n3;
            __syncthreads();
        }
    }

    // -- epilogue d-pair d0+9: slice d0+10 (in c) vs d0+9 (in p), !lastSeg only
    if (!lastSeg) {
        float dx0 = c1.x - p1.x, dx1 = c1.y - p1.y, dx2 = c1.z - p1.z, dx3 = c1.w - p1.w;
        float dy0 = c2.x - p2.x, dy1 = c2.y - p2.y, dy2 = c2.z - p2.z, dy3 = c2.w - p2.w;
        float dd = dx0*dx0 + dx1*dx1 + dx2*dx2 + dx3*dx3
                 + dy0*dy0 + dy1*dy1 + dy2*dy2 + dy3*dy3;
        for (int off = 32; off > 0; off >>= 1) dd += __shfl_down(dd, off, 64);
        if ((t & 63) == 0) atomicAdd(&accD[9], dd);
    }

    // -- flush per-thread register accumulators into LDS
    atomicAdd(&accH[r1], aH1);
    atomicAdd(&accH[r2], aH2);
    atomicAdd(&accW[fw * 4 + 0], aW0);
    atomicAdd(&accW[fw * 4 + 1], aW1);
    atomicAdd(&accW[fw * 4 + 2], aW2);
    if (fw < 39) atomicAdd(&accW[fw * 4 + 3], aW3);
    __syncthreads();

    // -- flush block accumulators to global workspace
    float* wsD = ws;
    float* wsH = ws + NB * NPAIR;
    float* wsW = ws + 2 * NB * NPAIR;
    const int nd = lastSeg ? 9 : 10;
    if (t < nd) atomicAdd(&wsD[b * NPAIR + d0 + t], accD[t]);
    if (t >= 32 && t < 48) {
        int r = t - 32;
        if (h0 + r < 159) atomicAdd(&wsH[b * NPAIR + h0 + r], accH[r]);
    }
    if (t >= 64 && t < 64 + 159) {
        int k = t - 64;
        atomicAdd(&wsW[b * NPAIR + k], accW[k]);
    }
}

__global__ __launch_bounds__(256) void finalize_kernel(const float* __restrict__ ws,
                                                       const float* __restrict__ log_sigma,
                                                       float* __restrict__ out) {
    __shared__ float ssum;
    const int t = threadIdx.x;
    if (t == 0) ssum = 0.f;
    __syncthreads();

    const float f0 = -0.5f * expf(-2.f * log_sigma[0]);  // -1/(2*sigma_d^2)
    const float f1 = -0.5f * expf(-2.f * log_sigma[1]);
    const float f2 = -0.5f * expf(-2.f * log_sigma[2]);

    float acc = 0.f;
    const int n = NB * NPAIR;  // 1272 per axis
    for (int i = t; i < n; i += 256) acc += expf(ws[i] * f0);
    for (int i = t; i < n; i += 256) acc += expf(ws[n + i] * f1);
    for (int i = t; i < n; i += 256) acc += expf(ws[2 * n + i] * f2);

    for (int off = 32; off > 0; off >>= 1) acc += __shfl_down(acc, off, 64);
    if ((t & 63) == 0) atomicAdd(&ssum, acc);
    __syncthreads();
    if (t == 0) out[0] = -ssum / (float)(3 * NB * NPAIR);
}

extern "C" void kernel_launch(void* const* d_in, const int* in_sizes, int n_in,
                              void* d_out, int out_size, void* d_ws, size_t ws_size,
                              hipStream_t stream) {
    const float* x = (const float*)d_in[0];
    const float* log_sigma = (const float*)d_in[1];
    float* out = (float*)d_out;
    float* ws = (float*)d_ws;

    zero_ws_kernel<<<(WS_FLOATS + 255) / 256, 256, 0, stream>>>(ws);
    diff3_kernel<<<8 * 10 * 16, 320, 0, stream>>>(x, ws);
    finalize_kernel<<<1, 256, 0, stream>>>(ws, log_sigma, out);
}

// Round 3
// 218.369 us; speedup vs baseline: 1.0112x; 1.0112x over previous
//
#include <hip/hip_runtime.h>

// x: [8, 1, 160, 160, 160] fp32; log_sigma: [3] fp32; out: scalar fp32.
// loss = -(mean_d(k) + mean_h(k) + mean_w(k)) / 3, k = exp(-sq/(2*sigma^2)),
// sq[b][pair] = sum over remaining dims of adjacent-slice squared diff.
//
// R3 design: NO LDS staging, NO per-iteration barriers. h-neighbor rows and
// w-boundary scalars are re-loaded from global (L1/L2 hits — stencil by
// reload). Waves run fully independent => memory-level parallelism never
// drains (R2 was latency-bound at 12% HBM: barrier vmcnt(0) drain per iter).

constexpr int Wd = 160;
constexpr int SLICE = 160 * 160;          // floats per (b,d) slice
constexpr long BSTRIDE = 160L * 25600;    // floats per batch
constexpr int NB = 8;
constexpr int NPAIR = 159;                // slice pairs per axis
constexpr int WS_FLOATS = 3 * NB * NPAIR; // 3816

__global__ void zero_ws_kernel(float* __restrict__ ws) {
    int i = blockIdx.x * 256 + threadIdx.x;
    if (i < WS_FLOATS) ws[i] = 0.f;
}

// Grid: 8 b * 10 h-chunks * 16 d-segments = 1280 blocks (5/CU), 320 threads.
// Thread t: float4 col fw=t%40, owns rows A=h0+t/40 and B=A+8 of each slice.
// Per slice loads: v1,v2 (owned), h1,h2 (row+1 reload), s1,s2 (w-boundary
// scalar). All diffs register-local; d-axis reduced per-wave via shfl, then
// LDS atomic (no barrier needed for atomics).
__global__ __launch_bounds__(320) void diff3_kernel(const float* __restrict__ x,
                                                    float* __restrict__ ws) {
    __shared__ float accD[10];
    __shared__ float accH[16];
    __shared__ float accW[160];

    const int t = threadIdx.x;
    const int bid = blockIdx.x;
    const int b = bid / 160;
    const int rem = bid % 160;
    const int s = rem / 10;    // d-segment 0..15
    const int hc = rem % 10;   // h-chunk 0..9
    const int h0 = hc * 16;
    const int d0 = s * 10;
    const bool lastSeg = (s == 15);          // no trailing d-halo slice

    const int fw = t % 40;
    const int r1 = t / 40;                   // 0..7
    const bool hOK2 = !(hc == 9 && r1 == 7); // row 159 has no h-pair
    const bool sOK = (fw < 39);              // col 156..159 has no w-boundary pair

    if (t < 10)              accD[t] = 0.f;
    if (t >= 32 && t < 48)   accH[t - 32] = 0.f;
    if (t >= 64 && t < 224)  accW[t - 64] = 0.f;
    __syncthreads();  // accumulators zeroed before any LDS atomic (only barrier until epilogue)

    const float* rowA = x + (size_t)b * BSTRIDE + (size_t)d0 * SLICE
                          + (size_t)(h0 + r1) * Wd + (size_t)fw * 4;
    const float* rowB = rowA + 8 * Wd;

    // ---- prologue: slice d0 ----
    float4 v1 = *(const float4*)rowA;
    float4 v2 = *(const float4*)rowB;
    float4 h1 = *(const float4*)(rowA + Wd);
    float4 h2;
    if (hOK2) h2 = *(const float4*)(rowB + Wd);
    float s1 = 0.f, s2 = 0.f;
    if (sOK) { s1 = rowA[4]; s2 = rowB[4]; }

    float4 p1, p2;
    float aH1 = 0.f, aH2 = 0.f;
    float aW0 = 0.f, aW1 = 0.f, aW2 = 0.f, aW3 = 0.f;

    for (int it = 0; it < 10; ++it) {
        // -- prefetch slice d0+it+1 (all loads issued before any compute)
        const bool hasNext = (it < 9) || !lastSeg;
        const float* nA = rowA + (size_t)(it + 1) * SLICE;
        const float* nB = rowB + (size_t)(it + 1) * SLICE;
        float4 nv1, nv2, nh1, nh2;
        float ns1 = 0.f, ns2 = 0.f;
        if (hasNext) {
            nv1 = *(const float4*)nA;
            nv2 = *(const float4*)nB;
        }
        if (it < 9) {
            nh1 = *(const float4*)(nA + Wd);
            if (hOK2) nh2 = *(const float4*)(nB + Wd);
            if (sOK) { ns1 = nA[4]; ns2 = nB[4]; }
        }

        // -- w-axis (register-local; boundary pair via scalar reload)
        float dw;
        dw = v1.y - v1.x; aW0 += dw * dw;
        dw = v1.z - v1.y; aW1 += dw * dw;
        dw = v1.w - v1.z; aW2 += dw * dw;
        dw = v2.y - v2.x; aW0 += dw * dw;
        dw = v2.z - v2.y; aW1 += dw * dw;
        dw = v2.w - v2.z; aW2 += dw * dw;
        if (sOK) {
            dw = s1 - v1.w; aW3 += dw * dw;
            dw = s2 - v2.w; aW3 += dw * dw;
        }
        // -- h-axis (neighbor row reloaded from global)
        {
            float e0 = h1.x - v1.x, e1 = h1.y - v1.y, e2 = h1.z - v1.z, e3 = h1.w - v1.w;
            aH1 += e0 * e0 + e1 * e1 + e2 * e2 + e3 * e3;
        }
        if (hOK2) {
            float e0 = h2.x - v2.x, e1 = h2.y - v2.y, e2 = h2.z - v2.z, e3 = h2.w - v2.w;
            aH2 += e0 * e0 + e1 * e1 + e2 * e2 + e3 * e3;
        }
        // -- d-axis: pair d0+it-1 (current vs previous slice, regs only)
        if (it > 0) {
            float dx0 = v1.x - p1.x, dx1 = v1.y - p1.y, dx2 = v1.z - p1.z, dx3 = v1.w - p1.w;
            float dy0 = v2.x - p2.x, dy1 = v2.y - p2.y, dy2 = v2.z - p2.z, dy3 = v2.w - p2.w;
            float dd = dx0*dx0 + dx1*dx1 + dx2*dx2 + dx3*dx3
                     + dy0*dy0 + dy1*dy1 + dy2*dy2 + dy3*dy3;
            for (int off = 32; off > 0; off >>= 1) dd += __shfl_down(dd, off, 64);
            if ((t & 63) == 0) atomicAdd(&accD[it - 1], dd);
        }

        p1 = v1; p2 = v2;
        if (hasNext) { v1 = nv1; v2 = nv2; }
        if (it < 9) {
            h1 = nh1;
            if (hOK2) h2 = nh2;
            if (sOK) { s1 = ns1; s2 = ns2; }
        }
    }

    // -- epilogue d-pair d0+9: slice d0+10 (in v) vs d0+9 (in p), !lastSeg only
    if (!lastSeg) {
        float dx0 = v1.x - p1.x, dx1 = v1.y - p1.y, dx2 = v1.z - p1.z, dx3 = v1.w - p1.w;
        float dy0 = v2.x - p2.x, dy1 = v2.y - p2.y, dy2 = v2.z - p2.z, dy3 = v2.w - p2.w;
        float dd = dx0*dx0 + dx1*dx1 + dx2*dx2 + dx3*dx3
                 + dy0*dy0 + dy1*dy1 + dy2*dy2 + dy3*dy3;
        for (int off = 32; off > 0; off >>= 1) dd += __shfl_down(dd, off, 64);
        if ((t & 63) == 0) atomicAdd(&accD[9], dd);
    }

    // -- flush per-thread register accumulators into LDS
    atomicAdd(&accH[r1], aH1);
    atomicAdd(&accH[r1 + 8], aH2);
    atomicAdd(&accW[fw * 4 + 0], aW0);
    atomicAdd(&accW[fw * 4 + 1], aW1);
    atomicAdd(&accW[fw * 4 + 2], aW2);
    if (sOK) atomicAdd(&accW[fw * 4 + 3], aW3);
    __syncthreads();

    // -- flush block accumulators to global workspace
    float* wsD = ws;
    float* wsH = ws + NB * NPAIR;
    float* wsW = ws + 2 * NB * NPAIR;
    const int nd = lastSeg ? 9 : 10;
    if (t < nd) atomicAdd(&wsD[b * NPAIR + d0 + t], accD[t]);
    if (t >= 32 && t < 48) {
        int r = t - 32;
        if (h0 + r < 159) atomicAdd(&wsH[b * NPAIR + h0 + r], accH[r]);
    }
    if (t >= 64 && t < 64 + 159) {
        int k = t - 64;
        atomicAdd(&wsW[b * NPAIR + k], accW[k]);
    }
}

__global__ __launch_bounds__(256) void finalize_kernel(const float* __restrict__ ws,
                                                       const float* __restrict__ log_sigma,
                                                       float* __restrict__ out) {
    __shared__ float ssum;
    const int t = threadIdx.x;
    if (t == 0) ssum = 0.f;
    __syncthreads();

    const float f0 = -0.5f * expf(-2.f * log_sigma[0]);  // -1/(2*sigma_d^2)
    const float f1 = -0.5f * expf(-2.f * log_sigma[1]);
    const float f2 = -0.5f * expf(-2.f * log_sigma[2]);

    float acc = 0.f;
    const int n = NB * NPAIR;  // 1272 per axis
    for (int i = t; i < n; i += 256) acc += expf(ws[i] * f0);
    for (int i = t; i < n; i += 256) acc += expf(ws[n + i] * f1);
    for (int i = t; i < n; i += 256) acc += expf(ws[2 * n + i] * f2);

    for (int off = 32; off > 0; off >>= 1) acc += __shfl_down(acc, off, 64);
    if ((t & 63) == 0) atomicAdd(&ssum, acc);
    __syncthreads();
    if (t == 0) out[0] = -ssum / (float)(3 * NB * NPAIR);
}

extern "C" void kernel_launch(void* const* d_in, const int* in_sizes, int n_in,
                              void* d_out, int out_size, void* d_ws, size_t ws_size,
                              hipStream_t stream) {
    const float* x = (const float*)d_in[0];
    const float* log_sigma = (const float*)d_in[1];
    float* out = (float*)d_out;
    float* ws = (float*)d_ws;

    zero_ws_kernel<<<(WS_FLOATS + 255) / 256, 256, 0, stream>>>(ws);
    diff3_kernel<<<8 * 10 * 16, 320, 0, stream>>>(x, ws);
    finalize_kernel<<<1, 256, 0, stream>>>(ws, log_sigma, out);
}